// Round 10
// baseline (459.427 us; speedup 1.0000x reference)
//
#include <hip/hip_runtime.h>

// CRS rate-and-state model. R -> et*R/(1+c*R) is a Mobius map [[a,0],[c,1]];
// maps compose associatively -> whole T=4096 row is ONE two-level scan:
// one 256-thread block per row, lane owns 16 contiguous steps.
// R10 = R9 minus the entire LDS store-bounce. R5's store penalty was SPARSITY
// (stride-64B 4-dword fragments -> 16 touched lines per instruction), not
// base misalignment. Direct per-thread nt dwordx4 stores at g0+16*tid give
// wave-contiguous 4KB spans: L2 write-combines full lines except <=2 edge
// lines per span. gfx950 supports unaligned global dwordx4. This removes:
// 33KB LDS (the 4-blocks/CU occupancy cap), 2 of 4 barriers, the LDS
// round-trip (+1.7M conflict cycles), and lets R stores overlap the N-scan.
// Keeps R9's nontemporal stores (L3 input retention: the 139->128 win).

#define C_TNSR  0.001f
#define C_TSSR  0.002f
#define C_SIGMA 50.0f
#define C_BIOT  0.3f
#define C_R0    0.0001f
#define C_N0    0.0001f

constexpr int B = 8192;
constexpr int T = 4096;
constexpr int STEPS = 16;          // per lane
constexpr int WAVES = 4;           // 256 threads per block = one row

typedef float f4  __attribute__((ext_vector_type(4)));
typedef float f4u __attribute__((ext_vector_type(4), aligned(4)));   // unaligned store vehicle

__global__ __launch_bounds__(256, 4)
void crs_row_kernel(const float* __restrict__ params,
                    const float* __restrict__ p,
                    const float* __restrict__ dpdt,
                    const float* __restrict__ dtv,
                    float* __restrict__ Rt,
                    float* __restrict__ Nt)
{
    __shared__ float sA[WAVES], sC[WAVES], sS[WAVES];

    const int tid  = threadIdx.x;
    const int lane = tid & 63;
    const int wid  = tid >> 6;
    const int b    = blockIdx.x;

    const float mu  = params[b * 3 + 0];
    const float rc  = params[b * 3 + 1];
    const float rf  = params[b * 3 + 2];
    const float eta = 1.0f / rf;
    const float rcS = rc * C_SIGMA;
    const float rcB = rc * C_BIOT;

    const int seg = tid * STEPS;
    const float* __restrict__ prow = p    + (size_t)b * T + seg;
    const float* __restrict__ drow = dpdt + (size_t)b * T + seg;
    const float* __restrict__ trow = dtv  + (size_t)b * T + seg;

    // ---- load this lane's 16 steps (64B-aligned dwordx4, dense) ----
    f4 pv[4], dv[4], tv[4];
#pragma unroll
    for (int q = 0; q < 4; ++q) pv[q] = *(const f4*)(prow + 4 * q);
#pragma unroll
    for (int q = 0; q < 4; ++q) dv[q] = *(const f4*)(drow + 4 * q);
#pragma unroll
    for (int q = 0; q < 4; ++q) tv[q] = *(const f4*)(trow + 4 * q);

    // ---- phase 1: per-lane inclusive Mobius prefixes ----
    float Aj[STEPS], Cj[STEPS], kk[STEPS];
    float A = 1.0f, C = 0.0f;
#pragma unroll
    for (int j = 0; j < STEPS; ++j) {
        float pp = pv[j >> 2][j & 3];
        float dd = dv[j >> 2][j & 3];
        float tt = tv[j >> 2][j & 3];
        float sd   = C_TSSR - mu * (C_TNSR - dd);
        float asig = fmaf(-rcB, pp, rcS);
        float e    = __expf(__fdividef(sd * tt, asig));
        float c    = __fdividef(eta * (e - 1.0f), sd);
        kk[j] = asig * rf;               // asig/eta
        C = fmaf(c, A, C);               // compose step j after (A,C)
        A = A * e;
        Aj[j] = A;
        Cj[j] = C;
    }

    // ---- phase 2a: wave-inclusive scan of (A,C) ----
#pragma unroll
    for (int o = 1; o < 64; o <<= 1) {
        float Ap = __shfl_up(A, (unsigned)o, 64);
        float Cp = __shfl_up(C, (unsigned)o, 64);
        if (lane >= o) { C = fmaf(C, Ap, Cp); A = A * Ap; }
    }
    float Ae = __shfl_up(A, 1u, 64);
    float Ce = __shfl_up(C, 1u, 64);
    if (lane == 0) { Ae = 1.0f; Ce = 0.0f; }

    // ---- phase 2b: cross-wave composition via LDS ----
    if (lane == 63) { sA[wid] = A; sC[wid] = C; }
    __syncthreads();
    float PA = 1.0f, PC = 0.0f;
#pragma unroll
    for (int w = 0; w < WAVES - 1; ++w) {
        if (w < wid) { PC = fmaf(sC[w], PA, PC); PA = sA[w] * PA; }
    }
    float EA = Ae * PA;
    float EC = fmaf(Ce, PA, PC);
    float Rt_ = __fdividef(EA * C_R0, fmaf(EC, C_R0, 1.0f));   // R entering segment

    // ---- output pointers (row base g0 is only dword-aligned; stores are
    //      per-thread dense dwordx4 -> wave-contiguous spans, L2 merges) ----
    const size_t g0 = (size_t)b * (T + 1) + 1;
    float* Rdst = Rt + g0 + seg;
    float* Ndst = Nt + g0 + seg;

    // ---- phase 3: closed-form R outputs, stored直接; N log terms ----
    // L_j = 1 + Cj*R~ ; R_j = Aj*R~/L_j ; den_j = L_j * rl_{j-1} (telescope)
    float nn[STEPS];
    float ns = 0.0f;
    float rlPrev = 1.0f;
    f4 rb;
#pragma unroll
    for (int j = 0; j < STEPS; ++j) {
        float L   = fmaf(Cj[j], Rt_, 1.0f);
        float rlj = __fdividef(1.0f, L);
        rb[j & 3] = (Aj[j] * Rt_) * rlj;
        float den = L * rlPrev;                        // == 1 + c_j*R_{j-1}
        ns += kk[j] * __logf(den);
        nn[j] = ns;
        rlPrev = rlj;
        if ((j & 3) == 3)
            __builtin_nontemporal_store(rb, (f4u*)(Rdst + (j - 3)));
    }

    if (tid == 0) {                                    // boundary column [0]
        __builtin_nontemporal_store(C_R0, Rt + g0 - 1);
        __builtin_nontemporal_store(C_N0, Nt + g0 - 1);
    }

    // ---- phase 4: two-level prefix sum of per-lane N totals ----
    float S = ns;
#pragma unroll
    for (int o = 1; o < 64; o <<= 1) {
        float Sp = __shfl_up(S, (unsigned)o, 64);
        if (lane >= o) S += Sp;
    }
    if (lane == 63) sS[wid] = S;
    __syncthreads();
    float PS = C_N0;
#pragma unroll
    for (int w = 0; w < WAVES - 1; ++w) {
        if (w < wid) PS += sS[w];
    }
    float base = PS + (S - ns);

#pragma unroll
    for (int q = 0; q < 4; ++q) {
        f4 nb;
#pragma unroll
        for (int c = 0; c < 4; ++c) nb[c] = base + nn[4 * q + c];
        __builtin_nontemporal_store(nb, (f4u*)(Ndst + 4 * q));
    }
}

extern "C" void kernel_launch(void* const* d_in, const int* in_sizes, int n_in,
                              void* d_out, int out_size, void* d_ws, size_t ws_size,
                              hipStream_t stream)
{
    const float* params = (const float*)d_in[0];
    const float* p      = (const float*)d_in[1];
    const float* dpdt   = (const float*)d_in[2];
    const float* dtv    = (const float*)d_in[3];

    float* Rt = (float*)d_out;                       // B*(T+1)
    float* Nt = (float*)d_out + (size_t)B * (T + 1); // B*(T+1)

    crs_row_kernel<<<B, 256, 0, stream>>>(params, p, dpdt, dtv, Rt, Nt);
}

// Round 11
// 126.319 us; speedup vs baseline: 3.6370x; 3.6370x over previous
//
#include <hip/hip_runtime.h>

// CRS rate-and-state model. R -> et*R/(1+c*R) is a Mobius map [[a,0],[c,1]];
// maps compose associatively -> whole T=4096 row is ONE two-level scan.
// R11 = R9 (best: 128us) with 512-thread blocks (STEPS 16->8, WAVES 8).
// R10 post-mortem: coalescing is per WAVE-INSTRUCTION; per-thread-contiguous
// f4 stores are per-instruction stride-64B sparse, and nt streams partial
// lines straight to HBM (WRITE 267->864MB). So the LDS bounce stays — it is
// what makes store instructions lane-contiguous. R9's limiter was occupancy:
// 34.3KB LDS capped 4 blocks/CU of 256 thr = 1024/2048 threads (34% meas).
// Same LDS with 512-thr blocks -> 4 blocks = 2048 threads = 100% ceiling.
// Per-thread arrays halve -> ~55 VGPR, under the 64-reg/8-wave cliff.
// Keeps: dual parallel R/N bounce, dword skew (2-way=free), per-row phase
// shift -> 64B-aligned f4 nt stores (L3 input retention: the 139->128 win).

#define C_TNSR  0.001f
#define C_TSSR  0.002f
#define C_SIGMA 50.0f
#define C_BIOT  0.3f
#define C_R0    0.0001f
#define C_N0    0.0001f

constexpr int B = 8192;
constexpr int T = 4096;
constexpr int STEPS = 8;           // per lane
constexpr int NTHR  = 512;         // threads per block = one row
constexpr int WAVES = NTHR / 64;   // 8

typedef float f4 __attribute__((ext_vector_type(4)));

__device__ __forceinline__ int SIDX(int m) { return m + (m >> 5); }

__global__ __launch_bounds__(NTHR, 4)
void crs_row_kernel(const float* __restrict__ params,
                    const float* __restrict__ p,
                    const float* __restrict__ dpdt,
                    const float* __restrict__ dtv,
                    float* __restrict__ Rt,
                    float* __restrict__ Nt)
{
    __shared__ float lsR[T + T / 32];   // 16.9 KB, skew-indexed
    __shared__ float lsN[T + T / 32];
    __shared__ float sA[WAVES], sC[WAVES], sS[WAVES];

    const int tid  = threadIdx.x;
    const int lane = tid & 63;
    const int wid  = tid >> 6;
    const int b    = blockIdx.x;

    const float mu  = params[b * 3 + 0];
    const float rc  = params[b * 3 + 1];
    const float rf  = params[b * 3 + 2];
    const float eta = 1.0f / rf;
    const float rcS = rc * C_SIGMA;
    const float rcB = rc * C_BIOT;

    const int seg = tid * STEPS;
    const float* __restrict__ prow = p    + (size_t)b * T + seg;
    const float* __restrict__ drow = dpdt + (size_t)b * T + seg;
    const float* __restrict__ trow = dtv  + (size_t)b * T + seg;

    // ---- load this lane's 8 steps (32B/lane dwordx4, dense) ----
    f4 pv[2], dv[2], tv[2];
#pragma unroll
    for (int q = 0; q < 2; ++q) pv[q] = *(const f4*)(prow + 4 * q);
#pragma unroll
    for (int q = 0; q < 2; ++q) dv[q] = *(const f4*)(drow + 4 * q);
#pragma unroll
    for (int q = 0; q < 2; ++q) tv[q] = *(const f4*)(trow + 4 * q);

    // ---- phase 1: per-lane inclusive Mobius prefixes ----
    float Aj[STEPS], Cj[STEPS], kk[STEPS];
    float A = 1.0f, C = 0.0f;
#pragma unroll
    for (int j = 0; j < STEPS; ++j) {
        float pp = pv[j >> 2][j & 3];
        float dd = dv[j >> 2][j & 3];
        float tt = tv[j >> 2][j & 3];
        float sd   = C_TSSR - mu * (C_TNSR - dd);
        float asig = fmaf(-rcB, pp, rcS);
        float e    = __expf(__fdividef(sd * tt, asig));
        float c    = __fdividef(eta * (e - 1.0f), sd);
        kk[j] = asig * rf;               // asig/eta
        C = fmaf(c, A, C);               // compose step j after (A,C)
        A = A * e;
        Aj[j] = A;
        Cj[j] = C;
    }

    // ---- phase 2a: wave-inclusive scan of (A,C) ----
#pragma unroll
    for (int o = 1; o < 64; o <<= 1) {
        float Ap = __shfl_up(A, (unsigned)o, 64);
        float Cp = __shfl_up(C, (unsigned)o, 64);
        if (lane >= o) { C = fmaf(C, Ap, Cp); A = A * Ap; }
    }
    float Ae = __shfl_up(A, 1u, 64);
    float Ce = __shfl_up(C, 1u, 64);
    if (lane == 0) { Ae = 1.0f; Ce = 0.0f; }

    // ---- phase 2b: cross-wave composition via LDS ----
    if (lane == 63) { sA[wid] = A; sC[wid] = C; }
    __syncthreads();
    float PA = 1.0f, PC = 0.0f;
#pragma unroll
    for (int w = 0; w < WAVES - 1; ++w) {
        if (w < wid) { PC = fmaf(sC[w], PA, PC); PA = sA[w] * PA; }
    }
    float EA = Ae * PA;
    float EC = fmaf(Ce, PA, PC);
    float Rt_ = __fdividef(EA * C_R0, fmaf(EC, C_R0, 1.0f));   // R entering segment

    // ---- phase 3: closed-form outputs; den telescopes: den_j = L_j * rl_{j-1} ----
    float nn[STEPS];
    float ns = 0.0f;
    float rlPrev = 1.0f;
#pragma unroll
    for (int j = 0; j < STEPS; ++j) {
        float L   = fmaf(Cj[j], Rt_, 1.0f);
        float rlj = __fdividef(1.0f, L);
        lsR[SIDX(seg + j)] = (Aj[j] * Rt_) * rlj;
        float den = L * rlPrev;                        // == 1 + c_j*R_{j-1}
        ns += kk[j] * __logf(den);
        nn[j] = ns;
        rlPrev = rlj;
    }

    // ---- phase 4: two-level prefix sum of per-lane N totals ----
    float S = ns;
#pragma unroll
    for (int o = 1; o < 64; o <<= 1) {
        float Sp = __shfl_up(S, (unsigned)o, 64);
        if (lane >= o) S += Sp;
    }
    if (lane == 63) sS[wid] = S;
    __syncthreads();
    float PS = C_N0;
#pragma unroll
    for (int w = 0; w < WAVES - 1; ++w) {
        if (w < wid) PS += sS[w];
    }
    float base = PS + (S - ns);
#pragma unroll
    for (int j = 0; j < STEPS; ++j)
        lsN[SIDX(seg + j)] = base + nn[j];

    __syncthreads();

    // ---- aligned store stage (all global stores NONTEMPORAL) ----
    const size_t g0 = (size_t)b * (T + 1) + 1;         // dword index of step 0
    const int s  = (int)((16 - (g0 & 15)) & 15);       // shift to 64B boundary
    const int tl = (T - s) & 3;                        // tail dwords
    const int bodyEnd = T - tl;

    if (tid == 0) {
        __builtin_nontemporal_store(C_R0, Rt + g0 - 1);
        __builtin_nontemporal_store(C_N0, Nt + g0 - 1);
    }
    if (tid < s) {
        __builtin_nontemporal_store(lsR[SIDX(tid)], Rt + g0 + tid);
        __builtin_nontemporal_store(lsN[SIDX(tid)], Nt + g0 + tid);
    }
    if (tid < tl) {
        int m = bodyEnd + tid;
        __builtin_nontemporal_store(lsR[SIDX(m)], Rt + g0 + m);
        __builtin_nontemporal_store(lsN[SIDX(m)], Nt + g0 + m);
    }

#pragma unroll
    for (int q = 0; q < 2; ++q) {                      // body: 64B-aligned f4
        int m0 = s + q * 2048 + tid * 4;
        if (m0 + 4 <= bodyEnd) {
            f4 r, n;
#pragma unroll
            for (int c = 0; c < 4; ++c) {
                r[c] = lsR[SIDX(m0 + c)];
                n[c] = lsN[SIDX(m0 + c)];
            }
            __builtin_nontemporal_store(r, (f4*)(Rt + g0 + m0));
            __builtin_nontemporal_store(n, (f4*)(Nt + g0 + m0));
        }
    }
}

extern "C" void kernel_launch(void* const* d_in, const int* in_sizes, int n_in,
                              void* d_out, int out_size, void* d_ws, size_t ws_size,
                              hipStream_t stream)
{
    const float* params = (const float*)d_in[0];
    const float* p      = (const float*)d_in[1];
    const float* dpdt   = (const float*)d_in[2];
    const float* dtv    = (const float*)d_in[3];

    float* Rt = (float*)d_out;                       // B*(T+1)
    float* Nt = (float*)d_out + (size_t)B * (T + 1); // B*(T+1)

    crs_row_kernel<<<B, NTHR, 0, stream>>>(params, p, dpdt, dtv, Rt, Nt);
}